// Round 4
// baseline (123.389 us; speedup 1.0000x reference)
//
#include <hip/hip_runtime.h>
#include <math.h>

#define GRID_N 5
#define LOG2E 1.4426950408889634f
#define EXP2F __builtin_amdgcn_exp2f

// Build per-(i,o) bin tables:
//   K = -s*log2e
//   A[k] = sum_{g_idx < k} w_g * 2^{-K*g},  B[k] = sum_{g_idx >= k} w_g * 2^{+K*g}
// T[i][k][o][2] = {A,B} (k=0..5);  Kt[i][o] = K
__device__ __forceinline__ void prep_one(const float* __restrict__ w,
                                         const float* __restrict__ s,
                                         float* __restrict__ T, float* __restrict__ Kt,
                                         int O, int I, int idx) {
    int o = idx / I, i = idx % I;               // w,s are [O][I(][G)]
    float K = -s[idx] * LOG2E;
    const float gv[5] = {-1.f, -0.5f, 0.f, 0.5f, 1.f};
    float A[6], B[6];
    A[0] = 0.f; B[5] = 0.f;
#pragma unroll
    for (int g = 0; g < 5; g++)
        A[g + 1] = A[g] + w[idx * GRID_N + g] * EXP2F(-K * gv[g]);
#pragma unroll
    for (int g = 4; g >= 0; g--)
        B[g] = B[g + 1] + w[idx * GRID_N + g] * EXP2F(K * gv[g]);
#pragma unroll
    for (int k = 0; k < 6; k++) {
        T[((i * 6 + k) * O + o) * 2 + 0] = A[k];
        T[((i * 6 + k) * O + o) * 2 + 1] = B[k];
    }
    Kt[i * O + o] = K;
}

__global__ __launch_bounds__(256) void prep_all(
    const float* __restrict__ w1, const float* __restrict__ s1, float* T1, float* K1,
    const float* __restrict__ w2, const float* __restrict__ s2, float* T2, float* K2,
    const float* __restrict__ w3, const float* __restrict__ s3, float* T3, float* K3) {
    int idx = blockIdx.x * 256 + threadIdx.x;
    if (idx < 32768)       prep_one(w1, s1, T1, K1, 256, 128, idx);
    else if (idx < 65536)  prep_one(w2, s2, T2, K2, 128, 256, idx - 32768);
    else if (idx < 73728)  prep_one(w3, s3, T3, K3,  64, 128, idx - 65536);
}

// out[b,o] = act( sum_i A[i,bin,o]*2^{K*xn} + B[i,bin,o]*2^{-K*xn} ),  xn = tanh(xin)
// Wave owns 64 consecutive o's (lane=o) x BPT b-rows. xn + precomputed 32-bit table
// byte-offset held lane-private (lane l <-> i=c*64+l), broadcast via v_readlane.
// Block's 4 waves share the same o-chunk (oc = wid/NBG) -> T-row L1 reuse across b.
template<int IN, int OUT, int ACT, int BPT>
__global__ __launch_bounds__(256) void kan_layer(
    const float* __restrict__ xin,   // [B][IN] raw (pre-tanh)
    const char*  __restrict__ Tb,    // [IN][6][OUT][2] floats, as bytes
    const float* __restrict__ Kt,    // [IN][OUT]
    float* __restrict__ out)         // [B][OUT]
{
    constexpr int CH  = IN / 64;
    constexpr int NBG = 2048 / BPT;            // b-groups (B=2048)
    constexpr unsigned ROWB = OUT * 8;         // bytes per (i,k) row

    const int lane = threadIdx.x & 63;
    const int wid  = (blockIdx.x << 2) | (threadIdx.x >> 6);
    const int oc   = wid / NBG;                // 4 block-waves share oc
    const int bg   = wid % NBG;
    const int o    = (oc << 6) | lane;
    const int b0   = bg * BPT;

    // per-lane tanh + full byte offset (i*6+bin)*ROWB  (lane l -> i = c*64+l)
    float    xv[BPT][CH];
    unsigned off[BPT][CH];
#pragma unroll
    for (int j = 0; j < BPT; j++)
#pragma unroll
        for (int c = 0; c < CH; c++) {
            int   i  = (c << 6) + lane;
            float v  = xin[(b0 + j) * IN + i];
            float ex = EXP2F(2.0f * LOG2E * v);
            float t  = 1.0f - 2.0f / (ex + 1.0f);       // tanh, NaN-safe
            xv[j][c] = t;
            int k = (int)((t + 1.0f) * 2.0f) + 1;       // #{g <= t}
            k = k > 5 ? 5 : k;
            off[j][c] = (unsigned)(i * 6 + k) * ROWB;
        }

    float acc[BPT];
#pragma unroll
    for (int j = 0; j < BPT; j++) acc[j] = 0.f;

    const unsigned o8 = (unsigned)o * 8u;
    const float*   Kp = Kt + o;

#pragma unroll
    for (int c = 0; c < CH; c++) {
#pragma unroll 8
        for (int l = 0; l < 64; l++) {
            const int i = (c << 6) + l;
            float K = Kp[i * OUT];                      // coalesced, amortized over BPT
#pragma unroll
            for (int j = 0; j < BPT; j++) {
                float    xs = __int_as_float(__builtin_amdgcn_readlane(__float_as_int(xv[j][c]), l));
                unsigned os = (unsigned)__builtin_amdgcn_readlane((int)off[j][c], l);
                const float2 ab = *(const float2*)(Tb + (os + o8));  // sgpr base + 32b voffset
                float t = K * xs;
                acc[j] += ab.x * EXP2F(t) + ab.y * EXP2F(-t);
            }
        }
    }

#pragma unroll
    for (int j = 0; j < BPT; j++) {
        float z = acc[j];
        if (ACT == 0) z = fmaxf(z, 0.f);
        else          z = 1.0f / (1.0f + EXP2F(-LOG2E * z));
        out[(b0 + j) * OUT + o] = z;
    }
}

extern "C" void kernel_launch(void* const* d_in, const int* in_sizes, int n_in,
                              void* d_out, int out_size, void* d_ws, size_t ws_size,
                              hipStream_t stream) {
    const float* x  = (const float*)d_in[0];
    const float* w1 = (const float*)d_in[1];
    const float* s1 = (const float*)d_in[2];
    const float* w2 = (const float*)d_in[3];
    const float* s2 = (const float*)d_in[4];
    const float* w3 = (const float*)d_in[5];
    const float* s3 = (const float*)d_in[6];
    float* out = (float*)d_out;

    float* ws  = (float*)d_ws;
    float* h1  = ws;                    // 2048*256            = 524288
    float* h2  = h1  + 524288;          // 2048*128            = 262144
    float* T1  = h2  + 262144;          // 128*6*256*2         = 393216
    float* K1  = T1  + 393216;          // 128*256             = 32768
    float* T2  = K1  + 32768;           // 256*6*128*2         = 393216
    float* K2  = T2  + 393216;          // 256*128             = 32768
    float* T3  = K2  + 32768;           // 128*6*64*2          = 98304
    float* K3  = T3  + 98304;           // 128*64              = 8192

    prep_all<<<288, 256, 0, stream>>>(w1, s1, T1, K1, w2, s2, T2, K2, w3, s3, T3, K3);

    // L1: OCH=4, BPT=2 -> 4096 waves, 1024 blocks (16 waves/CU)
    kan_layer<128, 256, 0, 2><<<1024, 256, 0, stream>>>(x,  (const char*)T1, K1, h1);
    // L2: OCH=2, BPT=2 -> 2048 waves, 512 blocks
    kan_layer<256, 128, 0, 2><<< 512, 256, 0, stream>>>(h1, (const char*)T2, K2, h2);
    // L3: OCH=1, BPT=1 -> 2048 waves, 512 blocks
    kan_layer<128,  64, 1, 1><<< 512, 256, 0, stream>>>(h2, (const char*)T3, K3, out);
}

// Round 5
// 96.773 us; speedup vs baseline: 1.2750x; 1.2750x over previous
//
#include <hip/hip_runtime.h>
#include <math.h>

#define GRID_N 5
#define LOG2E 1.4426950408889634f
#define EXP2F __builtin_amdgcn_exp2f

// Build per-(i,o) bin tables:
//   K = -s*log2e
//   A[k] = sum_{g_idx < k} w_g * 2^{-K*g},  B[k] = sum_{g_idx >= k} w_g * 2^{+K*g}
// T[i][k][o][2] = {A,B} (k=0..5);  Kt[i][o] = K
__device__ __forceinline__ void prep_one(const float* __restrict__ w,
                                         const float* __restrict__ s,
                                         float* __restrict__ T, float* __restrict__ Kt,
                                         int O, int I, int idx) {
    int o = idx / I, i = idx % I;               // w,s are [O][I(][G)]
    float K = -s[idx] * LOG2E;
    const float gv[5] = {-1.f, -0.5f, 0.f, 0.5f, 1.f};
    float A[6], B[6];
    A[0] = 0.f; B[5] = 0.f;
#pragma unroll
    for (int g = 0; g < 5; g++)
        A[g + 1] = A[g] + w[idx * GRID_N + g] * EXP2F(-K * gv[g]);
#pragma unroll
    for (int g = 4; g >= 0; g--)
        B[g] = B[g + 1] + w[idx * GRID_N + g] * EXP2F(K * gv[g]);
#pragma unroll
    for (int k = 0; k < 6; k++) {
        T[((i * 6 + k) * O + o) * 2 + 0] = A[k];
        T[((i * 6 + k) * O + o) * 2 + 1] = B[k];
    }
    Kt[i * O + o] = K;
}

__global__ __launch_bounds__(256) void prep_all(
    const float* __restrict__ w1, const float* __restrict__ s1, float* T1, float* K1,
    const float* __restrict__ w2, const float* __restrict__ s2, float* T2, float* K2,
    const float* __restrict__ w3, const float* __restrict__ s3, float* T3, float* K3) {
    int idx = blockIdx.x * 256 + threadIdx.x;
    if (idx < 32768)       prep_one(w1, s1, T1, K1, 256, 128, idx);
    else if (idx < 65536)  prep_one(w2, s2, T2, K2, 128, 256, idx - 32768);
    else if (idx < 73728)  prep_one(w3, s3, T3, K3,  64, 128, idx - 65536);
}

// out[b,o] = act( sum_i A[i,bin,o]*2^{K*xn} + B[i,bin,o]*2^{-K*xn} ),  xn = tanh(xin)
// Wave owns 64 consecutive o's (lane=o) x BPT b-rows. Block's 4 waves share the
// same o-chunk (K-line L1 reuse x4; AB bin-collision reuse across b).
// Inner loop: batches of 8 i's — issue 8*(BPT AB + 1 K) loads into explicit
// register arrays, THEN compute (2*8*BPT exp2 covers L2 latency).
template<int IN, int OUT, int ACT, int BPT>
__global__ __launch_bounds__(256, 4) void kan_layer(
    const float* __restrict__ xin,   // [B][IN] raw (pre-tanh)
    const char*  __restrict__ Tb,    // [IN][6][OUT][2] floats, as bytes
    const float* __restrict__ Kt,    // [IN][OUT]
    float* __restrict__ out)         // [B][OUT]
{
    constexpr int CH  = IN / 64;
    constexpr int NBG = 2048 / BPT;            // b-groups (B=2048)
    constexpr unsigned ROWB = OUT * 8;         // bytes per (i,k) row

    const int lane = threadIdx.x & 63;
    const int wid  = (blockIdx.x << 2) | (threadIdx.x >> 6);
    const int oc   = wid / NBG;                // 4 block-waves share oc
    const int bg   = wid % NBG;
    const int o    = (oc << 6) | lane;
    const int b0   = bg * BPT;

    // per-lane tanh + full byte offset (i*6+bin)*ROWB  (lane l -> i = c*64+l)
    float    xv[BPT][CH];
    unsigned off[BPT][CH];
#pragma unroll
    for (int j = 0; j < BPT; j++)
#pragma unroll
        for (int c = 0; c < CH; c++) {
            int   i  = (c << 6) + lane;
            float v  = xin[(b0 + j) * IN + i];
            float ex = EXP2F(2.0f * LOG2E * v);
            float t  = 1.0f - 2.0f / (ex + 1.0f);       // tanh, NaN-safe
            xv[j][c] = t;
            int k = (int)((t + 1.0f) * 2.0f) + 1;       // #{g <= t}
            k = k > 5 ? 5 : k;
            off[j][c] = (unsigned)(i * 6 + k) * ROWB;
        }

    float acc[BPT];
#pragma unroll
    for (int j = 0; j < BPT; j++) acc[j] = 0.f;

    const unsigned o8 = (unsigned)o * 8u;
    const float*   Kp = Kt + o;

#pragma unroll
    for (int c = 0; c < CH; c++) {
        for (int lb = 0; lb < 8; lb++) {       // dynamic batch loop: 8 i's/batch
            float2 ab[BPT][8];
            float  Kv[8];
#pragma unroll
            for (int u = 0; u < 8; u++) {
                const int l = lb * 8 + u;      // wave-uniform lane index
                const int i = (c << 6) + l;
                Kv[u] = Kp[i * OUT];
#pragma unroll
                for (int j = 0; j < BPT; j++) {
                    unsigned os = (unsigned)__builtin_amdgcn_readlane((int)off[j][c], l);
                    ab[j][u] = *(const float2*)(Tb + (os + o8));
                }
            }
#pragma unroll
            for (int u = 0; u < 8; u++) {
                const int l = lb * 8 + u;
#pragma unroll
                for (int j = 0; j < BPT; j++) {
                    float xs = __int_as_float(__builtin_amdgcn_readlane(__float_as_int(xv[j][c]), l));
                    float t  = Kv[u] * xs;
                    acc[j] += ab[j][u].x * EXP2F(t) + ab[j][u].y * EXP2F(-t);
                }
            }
        }
    }

#pragma unroll
    for (int j = 0; j < BPT; j++) {
        float z = acc[j];
        if (ACT == 0) z = fmaxf(z, 0.f);
        else          z = 1.0f / (1.0f + EXP2F(-LOG2E * z));
        out[(b0 + j) * OUT + o] = z;
    }
}

extern "C" void kernel_launch(void* const* d_in, const int* in_sizes, int n_in,
                              void* d_out, int out_size, void* d_ws, size_t ws_size,
                              hipStream_t stream) {
    const float* x  = (const float*)d_in[0];
    const float* w1 = (const float*)d_in[1];
    const float* s1 = (const float*)d_in[2];
    const float* w2 = (const float*)d_in[3];
    const float* s2 = (const float*)d_in[4];
    const float* w3 = (const float*)d_in[5];
    const float* s3 = (const float*)d_in[6];
    float* out = (float*)d_out;

    float* ws  = (float*)d_ws;
    float* h1  = ws;                    // 2048*256            = 524288
    float* h2  = h1  + 524288;          // 2048*128            = 262144
    float* T1  = h2  + 262144;          // 128*6*256*2         = 393216
    float* K1  = T1  + 393216;          // 128*256             = 32768
    float* T2  = K1  + 32768;           // 256*6*128*2         = 393216
    float* K2  = T2  + 393216;          // 256*128             = 32768
    float* T3  = K2  + 32768;           // 128*6*64*2          = 98304
    float* K3  = T3  + 98304;           // 128*64              = 8192

    prep_all<<<288, 256, 0, stream>>>(w1, s1, T1, K1, w2, s2, T2, K2, w3, s3, T3, K3);

    // L1: OCH=4, BPT=2 -> 4096 waves, 1024 blocks (16 waves/CU)
    kan_layer<128, 256, 0, 2><<<1024, 256, 0, stream>>>(x,  (const char*)T1, K1, h1);
    // L2: OCH=2, BPT=2 -> 2048 waves, 512 blocks (8 waves/CU)
    kan_layer<256, 128, 0, 2><<< 512, 256, 0, stream>>>(h1, (const char*)T2, K2, h2);
    // L3: OCH=1, BPT=1 -> 2048 waves, 512 blocks
    kan_layer<128,  64, 1, 1><<< 512, 256, 0, stream>>>(h2, (const char*)T3, K3, out);
}